// Round 13
// baseline (203.742 us; speedup 1.0000x reference)
//
#include <hip/hip_runtime.h>
#include <hip/hip_bf16.h>
#include <hip/hip_fp8.h>

// InfoNCE loss, N=8192 D=512 C=128.
// Fixed-shift softmax (M=10): t_ij = s_ij/tau - 10 in [-20, 0].
//   Z_i  = sum_{class!=} e^{t_ij}
//   term = -t_p + log(Z + e^{t_p}) ~= -t_p + logZ + e^{t_p}/Z
// r12 -> r13: revert to the r10 core (4 waves, best measured: 59.5us zgemm)
// and raise occupancy: ring-2 double buffer (exactly 32KB LDS; classes moved
// from LDS to regs) -> 5 blocks/CU = 20 waves/CU (launch_bounds(256,5),
// VGPR cap 102 > 72 observed -> no r11-style spill). Double-buffer hazard
// handled with 2 barriers/unit: lgkmcnt(0) -> barrier A -> STAGE(cur,kt+2);
// MFMA; vmcnt(4) -> barrier B. Counted vmcnt never drains mid-loop. fp8
// normed (4MB) is L2-resident (r10: 96% hit) so lead of ~1 unit suffices.
// fp8 interleaved layout + conflict-free b128 swizzle from r10 unchanged.

constexpr int   D      = 512;
constexpr int   BT     = 128;
constexpr int   BK     = 64;         // bytes (fp8 elems) per unit
constexpr int   NSTEP  = D / BK;     // 8
constexpr float TAUINV = 10.0f;
constexpr float SHIFT  = 10.0f;

typedef __attribute__((ext_vector_type(4))) float f32x4;
typedef __attribute__((ext_vector_type(2))) long i64x2;
typedef unsigned char uchar;
typedef unsigned long ulong_t;

__device__ inline uchar f2fp8(float x) {
    __hip_fp8_e4m3 h(x);             // OCP e4m3fn, RNE+sat via HW cvt
    return (uchar)h.__x;
}

__device__ inline void gload_lds16(const uchar* g, void* l) {
    __builtin_amdgcn_global_load_lds(
        (const __attribute__((address_space(1))) void*)g,
        (__attribute__((address_space(3))) void*)l, 16, 0, 0);
}

// ---------------- K1: L2-normalize rows, f32 -> fp8 (+hist in block 0) ----
// Output layout: per 64B k-block, chunk c (16B) = k[c*8..+8) ++ k[32+c*8..+8).
__global__ void k_normalize(const float* __restrict__ emb,
                            const int* __restrict__ classes,
                            uchar* __restrict__ normed,
                            int* __restrict__ hist, int n) {
    if (blockIdx.x == 0) {
        __shared__ int h[128];
        if (threadIdx.x < 128) h[threadIdx.x] = 0;
        __syncthreads();
        for (int i = threadIdx.x; i < n; i += 256)
            atomicAdd(&h[classes[i] & 127], 1);
        __syncthreads();
        if (threadIdx.x < 128) hist[threadIdx.x] = h[threadIdx.x];
    }
    int row  = blockIdx.x * 4 + (threadIdx.x >> 6);
    int lane = threadIdx.x & 63;
    if (row >= n) return;
    const float4* src = (const float4*)(emb + (size_t)row * D);
    float4 a = src[lane * 2];
    float4 b = src[lane * 2 + 1];
    float ss = a.x*a.x + a.y*a.y + a.z*a.z + a.w*a.w
             + b.x*b.x + b.y*b.y + b.z*b.z + b.w*b.w;
#pragma unroll
    for (int m = 1; m < 64; m <<= 1) ss += __shfl_xor(ss, m, 64);
    float sc = 1.0f / fmaxf(sqrtf(ss), 1e-12f);
    union { uchar c[8]; ulong_t u; } o;
    o.c[0] = f2fp8(a.x * sc); o.c[1] = f2fp8(a.y * sc);
    o.c[2] = f2fp8(a.z * sc); o.c[3] = f2fp8(a.w * sc);
    o.c[4] = f2fp8(b.x * sc); o.c[5] = f2fp8(b.y * sc);
    o.c[6] = f2fp8(b.z * sc); o.c[7] = f2fp8(b.w * sc);
    int j8   = lane & 7;
    int doff = (lane >> 3) * 64 + (j8 & 3) * 16 + (j8 >> 2) * 8;
    *(ulong_t*)&normed[(size_t)row * D + doff] = o.u;
}

// ---------------- K2: symmetric masked-exp fp8 GEMM, ring-2, 5 blk/CU ------
// Zpart: plane q in 0..2 (Z,NS,P1), each [64 slots][n rows].
__global__ __launch_bounds__(256, 5) void k_zgemm(
    const uchar* __restrict__ normed, const int* __restrict__ classes,
    float* __restrict__ Zpart, int n, int nb, int npairs) {
    __shared__ char ring[2][16384];           // exactly 32 KB

    const int tid  = threadIdx.x;
    const int lane = tid & 63;
    const int w    = tid >> 6;
    const int wm   = w >> 1, wn = w & 1;
    const int l15  = lane & 15, l4 = lane >> 4;
    const size_t QS = (size_t)64 * n;

    // XCD-chunked bijective swizzle
    int q8 = npairs >> 3, r8 = npairs & 7;
    int xcd = blockIdx.x & 7, off = blockIdx.x >> 3;
    int orig = (xcd < r8 ? xcd * (q8 + 1) : r8 * (q8 + 1) + (xcd - r8) * q8) + off;

    // orig -> (bi,bj) via 8x8 supertile walk (2D locality within an XCD)
    const int sgrid = nb >> 3;               // 8
    int idx = orig, si = 0;
    for (;;) { int rc = 36 + (sgrid - 1 - si) * 64; if (idx < rc) break; idx -= rc; ++si; }
    int bi, bj;
    if (idx < 36) { int u = 0, rem = 8; while (idx >= rem) { idx -= rem; ++u; --rem; }
                    bi = si * 8 + u; bj = si * 8 + u + idx; }
    else { idx -= 36; int sj = si + 1 + (idx >> 6); int v = idx & 63;
           bi = si * 8 + (v >> 3); bj = sj * 8 + (v & 7); }
    const int row0 = bi * BT, c0 = bj * BT;
    const bool diagblk = (bi == bj);

    // classes in registers (no LDS): row classes for this lane's 16 rows,
    // col classes for this lane's 4 column fragments.
    int crow[16];
#pragma unroll
    for (int t = 0; t < 16; ++t)
        crow[t] = classes[row0 + wm * 64 + (t >> 2) * 16 + l4 * 4 + (t & 3)];
    int ccv[4];
#pragma unroll
    for (int nf = 0; nf < 4; ++nf)
        ccv[nf] = classes[c0 + wn * 64 + nf * 16 + l15];

    // staging: chunk = 16 rows x 64B (1KB). wave w owns chunks {2w,2w+1}.
    // lane l: row = chunk*16 + (l>>2); LDS dst = base + lane*16 (linear).
    // 16B source slot pre-swizzled: src16 = (l&3) ^ ((l>>3)&3) (involution).
    const int src16 = (lane & 3) ^ ((lane >> 3) & 3);
    size_t gA[2], gB[2]; int lo[2];
#pragma unroll
    for (int it = 0; it < 2; ++it) {
        int chunk = w * 2 + it;
        int row   = chunk * 16 + (lane >> 2);
        gA[it] = (size_t)(row0 + row) * D + src16 * 16;
        gB[it] = (size_t)(c0   + row) * D + src16 * 16;
        lo[it] = chunk * 1024;
    }
    char* ringb = &ring[0][0];

    auto STAGE = [&](int sbo, int kk) {       // kk = unit * 64 (bytes)
#pragma unroll
        for (int it = 0; it < 2; ++it) {
            gload_lds16(normed + gA[it] + kk, ringb + sbo + lo[it]);
            gload_lds16(normed + gB[it] + kk, ringb + sbo + 8192 + lo[it]);
        }
    };

    f32x4 acc[4][4];
#pragma unroll
    for (int a = 0; a < 4; ++a)
#pragma unroll
        for (int b = 0; b < 4; ++b) acc[a][b] = (f32x4){0.f, 0.f, 0.f, 0.f};

    // prologue: both buffers staged; full drain once (robust vs class loads)
    STAGE(0, 0);
    STAGE(16384, BK);
    __builtin_amdgcn_sched_barrier(0);
    asm volatile("s_waitcnt vmcnt(0) lgkmcnt(0)" ::: "memory");
    __builtin_amdgcn_s_barrier();
    __builtin_amdgcn_sched_barrier(0);

    // b128 read: 16B slot = l4 ^ ((l15>>1)&3)  (conflict-free, r10-measured)
    const int rsw = (l15 >> 1) & 3;

#pragma unroll
    for (int kt = 0; kt < NSTEP; ++kt) {
        const int cur = kt & 1;
        const char* la = ringb + cur * 16384;
        const char* lb = la + 8192;
        i64x2 af[4], bfr[4];
#pragma unroll
        for (int mf = 0; mf < 4; ++mf) {
            int ra = wm * 64 + mf * 16 + l15;
            af[mf] = *(const i64x2*)(la + ra * 64 + ((l4 ^ rsw) << 4));
        }
#pragma unroll
        for (int nf = 0; nf < 4; ++nf) {
            int rb = wn * 64 + nf * 16 + l15;
            bfr[nf] = *(const i64x2*)(lb + rb * 64 + ((l4 ^ rsw) << 4));
        }
        asm volatile("s_waitcnt lgkmcnt(0)" ::: "memory");
        __builtin_amdgcn_sched_barrier(0);
        if (kt + 2 < NSTEP) {
            __builtin_amdgcn_s_barrier();     // A: all waves' reads retired
            __builtin_amdgcn_sched_barrier(0);
            STAGE(cur * 16384, (kt + 2) * BK);
        }
        __builtin_amdgcn_s_setprio(1);
#pragma unroll
        for (int mf = 0; mf < 4; ++mf)
#pragma unroll
            for (int nf = 0; nf < 4; ++nf) {
                acc[mf][nf] = __builtin_amdgcn_mfma_f32_16x16x32_fp8_fp8(
                    af[mf][0], bfr[nf][0], acc[mf][nf], 0, 0, 0);
                acc[mf][nf] = __builtin_amdgcn_mfma_f32_16x16x32_fp8_fp8(
                    af[mf][1], bfr[nf][1], acc[mf][nf], 0, 0, 0);
            }
        __builtin_amdgcn_s_setprio(0);
        __builtin_amdgcn_sched_barrier(0);
        if (kt + 2 < NSTEP)       asm volatile("s_waitcnt vmcnt(4)" ::: "memory");
        else if (kt + 2 == NSTEP) asm volatile("s_waitcnt vmcnt(0)" ::: "memory");
        if (kt + 1 < NSTEP) {
            __builtin_amdgcn_s_barrier();     // B: next unit's buffer ready
            __builtin_amdgcn_sched_barrier(0);
        }
    }
    __syncthreads();   // full drain before LDS overlay

    // ---- epilogue: masked accumulation of (Z, NS, P1) ----
    float cqz[4] = {0,0,0,0}, cqn[4] = {0,0,0,0}, cqp[4] = {0,0,0,0};
    float* redr = (float*)ringb;              // [2(wn)][128][3] = 3 KB
    float* redc = (float*)(ringb + 16384);    // [2(wm)][128][3] = 3 KB

#pragma unroll
    for (int mf = 0; mf < 4; ++mf) {
#pragma unroll
        for (int r = 0; r < 4; ++r) {
            int rr = wm * 64 + mf * 16 + l4 * 4 + r;
            int cr = crow[mf * 4 + r];
            float z = 0.f, ns = 0.f, p1 = 0.f;
#pragma unroll
            for (int nf = 0; nf < 4; ++nf) {
                int cc = wn * 64 + nf * 16 + l15;
                float t = fmaf(acc[mf][nf][r], TAUINV, -SHIFT);
                float e = __expf(t);
                bool same = (cr == ccv[nf]);
                bool dg   = diagblk && (rr == cc);
                if (!same) { z += e; cqz[nf] += e; }
                else if (!dg) { ns += t; p1 += e; cqn[nf] += t; cqp[nf] += e; }
            }
#pragma unroll
            for (int m = 1; m < 16; m <<= 1) {
                z  += __shfl_xor(z,  m, 16);
                ns += __shfl_xor(ns, m, 16);
                p1 += __shfl_xor(p1, m, 16);
            }
            if (l15 == 0) {
                float* p = &redr[(wn * 128 + rr) * 3];
                p[0] = z; p[1] = ns; p[2] = p1;
            }
        }
    }
    if (!diagblk) {
#pragma unroll
        for (int nf = 0; nf < 4; ++nf) {
            float z = cqz[nf], nsv = cqn[nf], p = cqp[nf];
            z += __shfl_xor(z, 16, 64);  z += __shfl_xor(z, 32, 64);
            nsv += __shfl_xor(nsv, 16, 64); nsv += __shfl_xor(nsv, 32, 64);
            p += __shfl_xor(p, 16, 64);  p += __shfl_xor(p, 32, 64);
            if (l4 == 0) {
                float* pp = &redc[(wm * 128 + wn * 64 + nf * 16 + l15) * 3];
                pp[0] = z; pp[1] = nsv; pp[2] = p;
            }
        }
    }
    __syncthreads();

    if (tid < BT) {                           // row-side partials, slot = bj
#pragma unroll
        for (int q = 0; q < 3; ++q)
            Zpart[q * QS + (size_t)bj * n + row0 + tid] =
                redr[(0 * 128 + tid) * 3 + q] + redr[(1 * 128 + tid) * 3 + q];
    } else if (!diagblk) {                    // col-side partials, slot = bi
        int cc = tid - BT;
#pragma unroll
        for (int q = 0; q < 3; ++q)
            Zpart[q * QS + (size_t)bi * n + c0 + cc] =
                redc[(0 * 128 + cc) * 3 + q] + redc[(1 * 128 + cc) * 3 + q];
    }
}

// ---------------- K3: per-row closed-form terms ----------------
__global__ void k_rowterms(const float* __restrict__ Zpart,
                           const int* __restrict__ classes,
                           const int* __restrict__ hist,
                           float* __restrict__ rowloss,
                           float* __restrict__ rowcnt, int n) {
    int i = blockIdx.x * 256 + threadIdx.x;
    if (i >= n) return;
    const size_t QS = (size_t)64 * n;
    float z = 0.f, ns = 0.f, p1 = 0.f;
    for (int s = 0; s < 64; ++s) {
        size_t o = (size_t)s * n + i;
        z  += Zpart[o];
        ns += Zpart[QS + o];
        p1 += Zpart[2 * QS + o];
    }
    float c = (float)(hist[classes[i] & 127] - 1);
    rowloss[i] = -ns + c * logf(z) + p1 / z;
    rowcnt[i]  = c;
}

// ---------------- K4: final deterministic reduction ----------------
__global__ void k_final(const float* __restrict__ rowloss,
                        const float* __restrict__ rowcnt,
                        float* __restrict__ out, int n) {
    __shared__ float sl[1024];
    __shared__ float sc[1024];
    float l = 0.f, c = 0.f;
    for (int i = threadIdx.x; i < n; i += 1024) {
        l += rowloss[i];
        c += rowcnt[i];
    }
    sl[threadIdx.x] = l;
    sc[threadIdx.x] = c;
    __syncthreads();
    for (int s = 512; s > 0; s >>= 1) {
        if (threadIdx.x < s) {
            sl[threadIdx.x] += sl[threadIdx.x + s];
            sc[threadIdx.x] += sc[threadIdx.x + s];
        }
        __syncthreads();
    }
    if (threadIdx.x == 0)
        out[0] = (sc[0] > 0.f) ? sl[0] / sc[0] : 0.f;
}

extern "C" void kernel_launch(void* const* d_in, const int* in_sizes, int n_in,
                              void* d_out, int out_size, void* d_ws, size_t ws_size,
                              hipStream_t stream) {
    const float* emb     = (const float*)d_in[0];
    const int*   classes = (const int*)d_in[1];
    float*       out     = (float*)d_out;
    const int n  = in_sizes[1];               // 8192
    const int nb = n / BT;                    // 64
    const int npairs = nb * (nb + 1) / 2;     // 2080

    uchar*  normed  = (uchar*)d_ws;                                    // 4 MB
    float*  Zpart   = (float*)((char*)d_ws + (size_t)n * D);           // 6 MB
    float*  rowloss = Zpart + (size_t)3 * 64 * n;
    float*  rowcnt  = rowloss + n;
    int*    hist    = (int*)(rowcnt + n);                              // 512 B

    k_normalize<<<n / 4, 256, 0, stream>>>(emb, classes, normed, hist, n);
    k_zgemm<<<npairs, 256, 0, stream>>>(normed, classes, Zpart, n, nb, npairs);
    k_rowterms<<<(n + 255) / 256, 256, 0, stream>>>(Zpart, classes, hist, rowloss, rowcnt, n);
    k_final<<<1, 1024, 0, stream>>>(rowloss, rowcnt, out, n);
}

// Round 14
// 75.841 us; speedup vs baseline: 2.6864x; 2.6864x over previous
//
#include <hip/hip_runtime.h>
#include <hip/hip_bf16.h>

// InfoNCE loss, N=8192 D=512 C=128.
// Fixed-shift softmax (M=10): t_ij = s_ij/tau - 10 in [-20, 0].
//   Z_i  = sum_{class!=} e^{t_ij}
//   term = -t_p + log(Z + e^{t_p}) ~= -t_p + logZ + e^{t_p}/Z
// r13 -> r14: revert to r10 (best measured: 59.5us zgemm, (256,3), ring-3,
// counted vmcnt(4), conflict-free b128 swizzle) and switch fp8 -> INT8:
// mfma_i32_16x16x64_i8 runs at 2x the fp8/bf16 rate (3944 TOPS, m16), K=64
// per instruction -> 16 MFMA/unit instead of 32, MFMA floor 17 -> 8.7us.
// i8 quantization (x127) of unit vectors: dot sigma ~3e-3 -> loss err << 1e-2
// (better than the passing e4m3). K=64 fragment = one contiguous 16B chunk
// (lane: l15=row, l4=k-slot) -> plain k-order layout, same b128 swizzle.
// Occupancy lesson (r11/r12/r13): do NOT raise launch_bounds; (256,3) only.

constexpr int   D      = 512;
constexpr int   BT     = 128;
constexpr int   BK     = 64;         // bytes (i8 elems) per unit
constexpr int   NSTEP  = D / BK;     // 8
constexpr float SHIFT  = 10.0f;
constexpr float QS2    = 10.0f / 16129.0f;   // (1/tau) / 127^2

typedef __attribute__((ext_vector_type(4))) int i32x4;
typedef unsigned char uchar;
typedef unsigned long ulong_t;

__device__ inline void gload_lds16(const uchar* g, void* l) {
    __builtin_amdgcn_global_load_lds(
        (const __attribute__((address_space(1))) void*)g,
        (__attribute__((address_space(3))) void*)l, 16, 0, 0);
}

// ---------------- K1: L2-normalize rows, f32 -> i8 (+hist in block 0) ----
__global__ void k_normalize(const float* __restrict__ emb,
                            const int* __restrict__ classes,
                            uchar* __restrict__ normed,
                            int* __restrict__ hist, int n) {
    if (blockIdx.x == 0) {
        __shared__ int h[128];
        if (threadIdx.x < 128) h[threadIdx.x] = 0;
        __syncthreads();
        for (int i = threadIdx.x; i < n; i += 256)
            atomicAdd(&h[classes[i] & 127], 1);
        __syncthreads();
        if (threadIdx.x < 128) hist[threadIdx.x] = h[threadIdx.x];
    }
    int row  = blockIdx.x * 4 + (threadIdx.x >> 6);
    int lane = threadIdx.x & 63;
    if (row >= n) return;
    const float4* src = (const float4*)(emb + (size_t)row * D);
    float4 a = src[lane * 2];
    float4 b = src[lane * 2 + 1];
    float ss = a.x*a.x + a.y*a.y + a.z*a.z + a.w*a.w
             + b.x*b.x + b.y*b.y + b.z*b.z + b.w*b.w;
#pragma unroll
    for (int m = 1; m < 64; m <<= 1) ss += __shfl_xor(ss, m, 64);
    float sc = 127.0f / fmaxf(sqrtf(ss), 1e-12f);
    union { signed char c[8]; ulong_t u; } o;
    float v[8] = {a.x, a.y, a.z, a.w, b.x, b.y, b.z, b.w};
#pragma unroll
    for (int k = 0; k < 8; ++k) {
        int q = (int)rintf(v[k] * sc);
        q = q > 127 ? 127 : (q < -127 ? -127 : q);
        o.c[k] = (signed char)q;
    }
    *(ulong_t*)&normed[(size_t)row * D + lane * 8] = o.u;
}

// ---------------- K2: symmetric masked-exp i8 GEMM, ring-3 pipeline -------
// Zpart: plane q in 0..2 (Z,NS,P1), each [64 slots][n rows].
__global__ __launch_bounds__(256, 3) void k_zgemm(
    const uchar* __restrict__ normed, const int* __restrict__ classes,
    float* __restrict__ Zpart, int n, int nb, int npairs) {
    __shared__ char ring[3][16384];           // 3 units x (A 8KB | B 8KB)
    __shared__ int clsrow[BT], clscol[BT];

    const int tid  = threadIdx.x;
    const int lane = tid & 63;
    const int w    = tid >> 6;
    const int wm   = w >> 1, wn = w & 1;
    const int l15  = lane & 15, l4 = lane >> 4;
    const size_t QS = (size_t)64 * n;

    // XCD-chunked bijective swizzle
    int q8 = npairs >> 3, r8 = npairs & 7;
    int xcd = blockIdx.x & 7, off = blockIdx.x >> 3;
    int orig = (xcd < r8 ? xcd * (q8 + 1) : r8 * (q8 + 1) + (xcd - r8) * q8) + off;

    // orig -> (bi,bj) via 8x8 supertile walk (2D locality within an XCD)
    const int sgrid = nb >> 3;               // 8
    int idx = orig, si = 0;
    for (;;) { int rc = 36 + (sgrid - 1 - si) * 64; if (idx < rc) break; idx -= rc; ++si; }
    int bi, bj;
    if (idx < 36) { int u = 0, rem = 8; while (idx >= rem) { idx -= rem; ++u; --rem; }
                    bi = si * 8 + u; bj = si * 8 + u + idx; }
    else { idx -= 36; int sj = si + 1 + (idx >> 6); int v = idx & 63;
           bi = si * 8 + (v >> 3); bj = sj * 8 + (v & 7); }
    const int row0 = bi * BT, c0 = bj * BT;
    const bool diagblk = (bi == bj);

    if (tid < BT) clsrow[tid] = classes[row0 + tid];
    else          clscol[tid - BT] = classes[c0 + tid - BT];
    int crow[16];
#pragma unroll
    for (int t = 0; t < 16; ++t)
        crow[t] = classes[row0 + wm * 64 + (t >> 2) * 16 + l4 * 4 + (t & 3)];

    // staging: chunk = 16 rows x 64B (1KB). wave w owns chunks {2w,2w+1}.
    // lane l: row = chunk*16 + (l>>2); LDS dst = base + lane*16 (linear).
    // 16B source slot pre-swizzled: src16 = (l&3) ^ ((l>>3)&3) (involution).
    const int src16 = (lane & 3) ^ ((lane >> 3) & 3);
    size_t gA[2], gB[2]; int lo[2];
#pragma unroll
    for (int it = 0; it < 2; ++it) {
        int chunk = w * 2 + it;
        int row   = chunk * 16 + (lane >> 2);
        gA[it] = (size_t)(row0 + row) * D + src16 * 16;
        gB[it] = (size_t)(c0   + row) * D + src16 * 16;
        lo[it] = chunk * 1024;
    }
    char* ringb = &ring[0][0];

    auto STAGE = [&](int sbo, int kk) {       // kk = unit * 64 (bytes)
#pragma unroll
        for (int it = 0; it < 2; ++it) {
            gload_lds16(normed + gA[it] + kk, ringb + sbo + lo[it]);
            gload_lds16(normed + gB[it] + kk, ringb + sbo + 8192 + lo[it]);
        }
    };

    i32x4 acc[4][4];
#pragma unroll
    for (int a = 0; a < 4; ++a)
#pragma unroll
        for (int b = 0; b < 4; ++b) acc[a][b] = (i32x4){0, 0, 0, 0};

    STAGE(0, 0);
    STAGE(16384, BK);
    __builtin_amdgcn_sched_barrier(0);
    asm volatile("s_waitcnt vmcnt(4) lgkmcnt(0)" ::: "memory");
    __builtin_amdgcn_s_barrier();
    __builtin_amdgcn_sched_barrier(0);

    // b128 read: 16B slot = l4 ^ ((l15>>1)&3)  (conflict-free, r10-measured)
    const int rsw = (l15 >> 1) & 3;

#pragma unroll
    for (int kt = 0; kt < NSTEP; ++kt) {
        const int cur = kt % 3;
        if (kt + 2 < NSTEP) STAGE(((kt + 2) % 3) * 16384, (kt + 2) * BK);
        const char* la = ringb + cur * 16384;
        const char* lb = la + 8192;
        i32x4 af[4], bfr[4];
#pragma unroll
        for (int mf = 0; mf < 4; ++mf) {
            int ra = wm * 64 + mf * 16 + l15;
            af[mf] = *(const i32x4*)(la + ra * 64 + ((l4 ^ rsw) << 4));
        }
#pragma unroll
        for (int nf = 0; nf < 4; ++nf) {
            int rb = wn * 64 + nf * 16 + l15;
            bfr[nf] = *(const i32x4*)(lb + rb * 64 + ((l4 ^ rsw) << 4));
        }
        __builtin_amdgcn_s_setprio(1);
#pragma unroll
        for (int mf = 0; mf < 4; ++mf)
#pragma unroll
            for (int nf = 0; nf < 4; ++nf)
                acc[mf][nf] = __builtin_amdgcn_mfma_i32_16x16x64_i8(
                    af[mf], bfr[nf], acc[mf][nf], 0, 0, 0);
        __builtin_amdgcn_s_setprio(0);
        __builtin_amdgcn_sched_barrier(0);
        if (kt + 2 < NSTEP)       asm volatile("s_waitcnt vmcnt(4)" ::: "memory");
        else if (kt + 2 == NSTEP) asm volatile("s_waitcnt vmcnt(0)" ::: "memory");
        if (kt + 1 < NSTEP) {
            __builtin_amdgcn_s_barrier();
            __builtin_amdgcn_sched_barrier(0);
        }
    }
    __syncthreads();   // full drain before LDS overlay

    // ---- epilogue: masked accumulation of (Z, NS, P1) ----
    float cqz[4] = {0,0,0,0}, cqn[4] = {0,0,0,0}, cqp[4] = {0,0,0,0};
    float* redr = (float*)ringb;              // [2(wn)][128][3]
    float* redc = (float*)(ringb + 16384);    // [2(wm)][128][3]

#pragma unroll
    for (int mf = 0; mf < 4; ++mf) {
#pragma unroll
        for (int r = 0; r < 4; ++r) {
            int rr = wm * 64 + mf * 16 + l4 * 4 + r;
            int rg = row0 + rr;
            int cr = crow[mf * 4 + r];
            float z = 0.f, ns = 0.f, p1 = 0.f;
#pragma unroll
            for (int nf = 0; nf < 4; ++nf) {
                int cc = wn * 64 + nf * 16 + l15;
                float t = fmaf((float)acc[mf][nf][r], QS2, -SHIFT);
                float e = __expf(t);
                bool same = (cr == clscol[cc]);
                bool dg   = (rg == c0 + cc);
                if (!same) { z += e; cqz[nf] += e; }
                else if (!dg) { ns += t; p1 += e; cqn[nf] += t; cqp[nf] += e; }
            }
#pragma unroll
            for (int m = 1; m < 16; m <<= 1) {
                z  += __shfl_xor(z,  m, 16);
                ns += __shfl_xor(ns, m, 16);
                p1 += __shfl_xor(p1, m, 16);
            }
            if (l15 == 0) {
                float* p = &redr[(wn * 128 + rr) * 3];
                p[0] = z; p[1] = ns; p[2] = p1;
            }
        }
    }
    if (!diagblk) {
#pragma unroll
        for (int nf = 0; nf < 4; ++nf) {
            float z = cqz[nf], nsv = cqn[nf], p = cqp[nf];
            z += __shfl_xor(z, 16, 64);  z += __shfl_xor(z, 32, 64);
            nsv += __shfl_xor(nsv, 16, 64); nsv += __shfl_xor(nsv, 32, 64);
            p += __shfl_xor(p, 16, 64);  p += __shfl_xor(p, 32, 64);
            if (l4 == 0) {
                float* pp = &redc[(wm * 128 + wn * 64 + nf * 16 + l15) * 3];
                pp[0] = z; pp[1] = nsv; pp[2] = p;
            }
        }
    }
    __syncthreads();

    if (tid < BT) {                           // row-side partials, slot = bj
#pragma unroll
        for (int q = 0; q < 3; ++q)
            Zpart[q * QS + (size_t)bj * n + row0 + tid] =
                redr[(0 * 128 + tid) * 3 + q] + redr[(1 * 128 + tid) * 3 + q];
    } else if (!diagblk) {                    // col-side partials, slot = bi
        int cc = tid - BT;
#pragma unroll
        for (int q = 0; q < 3; ++q)
            Zpart[q * QS + (size_t)bi * n + c0 + cc] =
                redc[(0 * 128 + cc) * 3 + q] + redc[(1 * 128 + cc) * 3 + q];
    }
}

// ---------------- K3: per-row closed-form terms ----------------
__global__ void k_rowterms(const float* __restrict__ Zpart,
                           const int* __restrict__ classes,
                           const int* __restrict__ hist,
                           float* __restrict__ rowloss,
                           float* __restrict__ rowcnt, int n) {
    int i = blockIdx.x * 256 + threadIdx.x;
    if (i >= n) return;
    const size_t QS = (size_t)64 * n;
    float z = 0.f, ns = 0.f, p1 = 0.f;
    for (int s = 0; s < 64; ++s) {
        size_t o = (size_t)s * n + i;
        z  += Zpart[o];
        ns += Zpart[QS + o];
        p1 += Zpart[2 * QS + o];
    }
    float c = (float)(hist[classes[i] & 127] - 1);
    rowloss[i] = -ns + c * logf(z) + p1 / z;
    rowcnt[i]  = c;
}

// ---------------- K4: final deterministic reduction ----------------
__global__ void k_final(const float* __restrict__ rowloss,
                        const float* __restrict__ rowcnt,
                        float* __restrict__ out, int n) {
    __shared__ float sl[1024];
    __shared__ float sc[1024];
    float l = 0.f, c = 0.f;
    for (int i = threadIdx.x; i < n; i += 1024) {
        l += rowloss[i];
        c += rowcnt[i];
    }
    sl[threadIdx.x] = l;
    sc[threadIdx.x] = c;
    __syncthreads();
    for (int s = 512; s > 0; s >>= 1) {
        if (threadIdx.x < s) {
            sl[threadIdx.x] += sl[threadIdx.x + s];
            sc[threadIdx.x] += sc[threadIdx.x + s];
        }
        __syncthreads();
    }
    if (threadIdx.x == 0)
        out[0] = (sc[0] > 0.f) ? sl[0] / sc[0] : 0.f;
}

extern "C" void kernel_launch(void* const* d_in, const int* in_sizes, int n_in,
                              void* d_out, int out_size, void* d_ws, size_t ws_size,
                              hipStream_t stream) {
    const float* emb     = (const float*)d_in[0];
    const int*   classes = (const int*)d_in[1];
    float*       out     = (float*)d_out;
    const int n  = in_sizes[1];               // 8192
    const int nb = n / BT;                    // 64
    const int npairs = nb * (nb + 1) / 2;     // 2080

    uchar*  normed  = (uchar*)d_ws;                                    // 4 MB
    float*  Zpart   = (float*)((char*)d_ws + (size_t)n * D);           // 6 MB
    float*  rowloss = Zpart + (size_t)3 * 64 * n;
    float*  rowcnt  = rowloss + n;
    int*    hist    = (int*)(rowcnt + n);                              // 512 B

    k_normalize<<<n / 4, 256, 0, stream>>>(emb, classes, normed, hist, n);
    k_zgemm<<<npairs, 256, 0, stream>>>(normed, classes, Zpart, n, nb, npairs);
    k_rowterms<<<(n + 255) / 256, 256, 0, stream>>>(Zpart, classes, hist, rowloss, rowcnt, n);
    k_final<<<1, 1024, 0, stream>>>(rowloss, rowcnt, out, n);
}